// Round 6
// baseline (384.148 us; speedup 1.0000x reference)
//
#include <hip/hip_runtime.h>

#define NS 4096
#define IND 768
#define PP 64
#define DD 256
#define EPSF 1e-8f

typedef float f32x4 __attribute__((ext_vector_type(4)));

// ==== single fused kernel: per-block GEMM (8 rows) + norms + cos/dist + token
//      write + global reductions + last-block loss finalize ====
// 512 blocks x 256 threads. LDS 64+8+1.3 KB -> 2 blocks/CU.
// No cross-block dependencies: ticket-511 block reads accumulators only after
// every block's atomics (barrier -> fence -> ticket ordering). Deadlock-free.
// accum: [0]=s_pz [1]=s_cl [2]=s_num [3]=pp_dist_total [4]=ticket(uint)
__global__ __launch_bounds__(256) void k_fused(const float* __restrict__ x,
                                               const float* __restrict__ W,
                                               const float* __restrict__ bias,
                                               const float* __restrict__ protos,
                                               const int* __restrict__ labels,
                                               float* __restrict__ out,
                                               unsigned int* __restrict__ minu,
                                               float* __restrict__ accum,
                                               int out_last) {
    __shared__ f32x4 protoT4[PP * 64];               // [p*64 + (db ^ (p&7))], 64 KB
    __shared__ __align__(16) float rowbuf[8][DD];    // z rows for this block, 8 KB
    __shared__ float wmin[4][64];
    __shared__ float wacc[4][3];
    int tid = threadIdx.x;
    int bid = blockIdx.x;
    int nbase = bid * 8;

    // proto staging (independent; overlaps the GEMM phase's loads)
    const f32x4* pr4g = (const f32x4*)protos;
    for (int idx = tid; idx < PP * 64; idx += 256) {
        int pp = idx >> 6, db = idx & 63;
        protoT4[pp * 64 + (db ^ (pp & 7))] = pr4g[idx];
    }

    float bv = bias[tid];

    // ---- GEMM: z[r][tid] = x[nbase+r][:] . W[:][tid], r=0..7 ----
    // x addresses are wave-uniform (scalar-cache loads); W coalesced 256B/wave.
    // Same total FLOPs as a tiled GEMM (512 blocks x 8 rows covers N exactly once);
    // W (786 KB) is L2-resident per XCD, so per-block re-streaming is L2-hit.
    const float* xr = x + (size_t)nbase * IND;
    const float* wp = W + tid;
    float c[8] = {};
    f32x4 xv[8];
    float w0, w1, w2, w3;
#pragma unroll
    for (int r = 0; r < 8; ++r) xv[r] = *(const f32x4*)&xr[r * IND];
    w0 = wp[0 * DD]; w1 = wp[1 * DD]; w2 = wp[2 * DD]; w3 = wp[3 * DD];
    for (int k4 = 0; k4 < IND / 4; ++k4) {
        f32x4 cx[8];
        float cw0 = w0, cw1 = w1, cw2 = w2, cw3 = w3;
#pragma unroll
        for (int r = 0; r < 8; ++r) cx[r] = xv[r];
        if (k4 + 1 < IND / 4) {  // prefetch next k-quad (x scalar, W vector)
            int k = (k4 + 1) * 4;
#pragma unroll
            for (int r = 0; r < 8; ++r) xv[r] = *(const f32x4*)&xr[r * IND + k];
            w0 = wp[(size_t)(k + 0) * DD]; w1 = wp[(size_t)(k + 1) * DD];
            w2 = wp[(size_t)(k + 2) * DD]; w3 = wp[(size_t)(k + 3) * DD];
        }
#pragma unroll
        for (int r = 0; r < 8; ++r)
            c[r] += cx[r].x * cw0 + cx[r].y * cw1 + cx[r].z * cw2 + cx[r].w * cw3;
    }
#pragma unroll
    for (int r = 0; r < 8; ++r) rowbuf[r][tid] = c[r] + bv;
    __syncthreads();  // rowbuf + protoT4 ready; the ONLY pre-store barrier

    int w = tid >> 6, lane = tid & 63;
    int p = lane;

    // ---- z norms: wave w owns samples 2w, 2w+1 ----
    float zn[2];
#pragma unroll
    for (int s = 0; s < 2; ++s) {
        f32x4 r4 = ((const f32x4*)rowbuf[2 * w + s])[lane];
        float ss = r4.x * r4.x + r4.y * r4.y + r4.z * r4.z + r4.w * r4.w;
#pragma unroll
        for (int o = 1; o < 64; o <<= 1) ss += __shfl_xor(ss, o);
        zn[s] = sqrtf(ss);
    }

    // ---- dots (lane = prototype); pnorm^2 folded in (free under LDS issue) ----
    float dot0 = 0.f, dot1 = 0.f, pp2 = 0.f;
#pragma unroll 8
    for (int d4 = 0; d4 < 64; ++d4) {
        f32x4 r0 = ((const f32x4*)rowbuf[2 * w + 0])[d4];  // broadcast
        f32x4 r1 = ((const f32x4*)rowbuf[2 * w + 1])[d4];
        f32x4 pv = protoT4[p * 64 + (d4 ^ (p & 7))];       // bank-even b128
        dot0 += r0.x * pv.x + r0.y * pv.y + r0.z * pv.z + r0.w * pv.w;
        dot1 += r1.x * pv.x + r1.y * pv.y + r1.z * pv.z + r1.w * pv.w;
        pp2  += pv.x * pv.x + pv.y * pv.y + pv.z * pv.z + pv.w * pv.w;
    }
    float pn = sqrtf(pp2);
    float dots[2] = {dot0, dot1};

    float cosv[2];
    float regmin = 3.4e38f;
    float s_pz = 0.f, s_cl = 0.f, s_num = 0.f;
#pragma unroll
    for (int s = 0; s < 2; ++s) {
        int n = nbase + 2 * w + s;
        float dot = dots[s];
        float cs = dot / (fmaxf(zn[s], EPSF) * fmaxf(pn, EPSF));
        cosv[s] = cs;
        float d2 = zn[s] * zn[s] + pp2 - 2.f * dot;
        float dist = sqrtf(fmaxf(d2, 0.f));
        regmin = fminf(regmin, dist);

        unsigned long long bal = __ballot(cs > 0.5f);
        int cnt = __popcll(bal);

        float mind = dist;
#pragma unroll
        for (int o = 1; o < 64; o <<= 1) mind = fminf(mind, __shfl_xor(mind, o));
        float mx = cs;
#pragma unroll
        for (int o = 1; o < 32; o <<= 1) mx = fmaxf(mx, __shfl_xor(mx, o));
        float max_pos = __shfl(mx, 0);
        float max_neg = __shfl(mx, 32);
        if (lane == 0) {
            float dcl = (labels[n] == 1) ? (1.f - max_pos) : (1.f - max_neg);
            s_pz += mind;
            s_cl += dcl;
            if (cnt > 16) s_num += 1.f;
        }
    }

    // ---- token write (NT stores, measured best): starts right after dots ----
    {
        const f32x4* pr4 = (const f32x4*)protos;
        f32x4* o0 = (f32x4*)out + (size_t)(nbase + 2 * w + 0) * 4096 + lane;
        f32x4* o1 = (f32x4*)out + (size_t)(nbase + 2 * w + 1) * 4096 + lane;
        float cv0 = cosv[0], cv1 = cosv[1];
#pragma unroll 8
        for (int pp = 0; pp < 64; ++pp) {
            f32x4 v = pr4[pp * 64 + lane];
            float c0 = __shfl(cv0, pp);
            float c1 = __shfl(cv1, pp);
            __builtin_nontemporal_store(c0 * v, &o0[pp * 64]);
            __builtin_nontemporal_store(c1 * v, &o1[pp * 64]);
        }
    }

    // ---- block-level reduction, one atomic set per block ----
    wmin[w][lane] = regmin;
    if (lane == 0) { wacc[w][0] = s_pz; wacc[w][1] = s_cl; wacc[w][2] = s_num; }
    __syncthreads();
    if (w == 0) {
        float m = fminf(fminf(wmin[0][lane], wmin[1][lane]),
                        fminf(wmin[2][lane], wmin[3][lane]));
        atomicMin(&minu[lane], __float_as_uint(m));
        if (lane == 0) {
            atomicAdd(&accum[0], wacc[0][0] + wacc[1][0] + wacc[2][0] + wacc[3][0]);
            atomicAdd(&accum[1], wacc[0][1] + wacc[1][1] + wacc[2][1] + wacc[3][1]);
            atomicAdd(&accum[2], wacc[0][2] + wacc[1][2] + wacc[2][2] + wacc[3][2]);
        }
    }

    // ---- prototype pairwise distances: blocks 0..63, one row-sum each ----
    if (bid < PP) {
        int q = tid >> 2, quarter = tid & 3;
        const float* pr = protos + bid * DD + quarter * 64;
        const float* qr = protos + q * DD + quarter * 64;
        float s2 = 0.f;
        for (int d = 0; d < 64; ++d) { float diff = pr[d] - qr[d]; s2 += diff * diff; }
        s2 += __shfl_xor(s2, 1);
        s2 += __shfl_xor(s2, 2);
        float contrib = (quarter == 0 && q != bid) ? sqrtf(s2) : 0.f;
#pragma unroll
        for (int o = 1; o < 64; o <<= 1) contrib += __shfl_xor(contrib, o);
        if (lane == 0) atomicAdd(&accum[3], contrib);  // 4 adds (one per wave)
    }

    // ---- ticket: barrier (intra-block HB) -> fence (publish) -> count ----
    __syncthreads();
    if (w == 0) {
        __threadfence();
        unsigned int t = 0;
        if (lane == 0) t = atomicAdd((unsigned int*)accum + 4, 1u);
        t = __shfl(t, 0);
        if (t == 511u) {  // last block finalizes the scalar loss
            __threadfence();
            // atomic no-op reads: coherent with all blocks' device-scope atomics
            float mv = __uint_as_float(atomicMin(&minu[lane], 0xFFFFFFFFu));
            float v = mv * (1.f / PP);
#pragma unroll
            for (int o = 1; o < 64; o <<= 1) v += __shfl_xor(v, o);
            if (lane == 0) {
                float l_pp = atomicAdd(&accum[3], 0.f) * (1.f / (PP * (PP - 1)));
                float l_pz = atomicAdd(&accum[0], 0.f) * (1.f / NS);
                float l_cl = atomicAdd(&accum[1], 0.f) * (1.f / NS);
                float l_num = atomicAdd(&accum[2], 0.f);
                out[out_last] = v + l_pp + l_pz + l_num + 2.f * l_cl;
            }
        }
    }
}

extern "C" void kernel_launch(void* const* d_in, const int* in_sizes, int n_in,
                              void* d_out, int out_size, void* d_ws, size_t ws_size,
                              hipStream_t stream) {
    const float* x      = (const float*)d_in[0];
    const int*   labels = (const int*)d_in[1];
    const float* W      = (const float*)d_in[2];
    const float* bias   = (const float*)d_in[3];
    const float* protos = (const float*)d_in[4];
    float* out = (float*)d_out;
    float* ws = (float*)d_ws;

    unsigned int* minu = (unsigned int*)ws;   // 64 slots
    float* accum = ws + 64;                   // 4 float sums + 1 uint ticket

    hipMemsetAsync(minu, 0xFF, 64 * sizeof(unsigned int), stream);  // +inf bits
    hipMemsetAsync(accum, 0, 5 * sizeof(float), stream);
    k_fused<<<512, 256, 0, stream>>>(x, W, bias, protos, labels, out,
                                     minu, accum, out_size - 1);
}